// Round 1
// baseline (410.401 us; speedup 1.0000x reference)
//
#include <hip/hip_runtime.h>
#include <math.h>

// Problem constants (fixed by the reference file)
constexpr int B = 256;
constexpr int L = 1024;
constexpr int D = 512;
constexpr int DV = D / 4;                         // 128 float4 per row
constexpr float INV_T = 0.044194173824159216f;    // 1/sqrt(512)

__global__ __launch_bounds__(1024) void cda_fused_kernel(
    const float* __restrict__ q,    // (B,1,D)
    const float* __restrict__ kc,   // (B,L,D)
    const float* __restrict__ kd,   // (B,L,D)
    const float* __restrict__ v,    // (B,L,D)
    float* __restrict__ out,        // (B,L,D)
    float* __restrict__ logits)     // (B,L)
{
    const int b    = blockIdx.x;
    const int tid  = threadIdx.x;
    const int lane = tid & 63;
    const int wave = tid >> 6;      // 0..15

    __shared__ float  s_col[L];        // col logits -> softmax weights (4 KB)
    __shared__ float  s_sig[L];        // sigmoid gates (4 KB)
    __shared__ float4 s_part[8][DV];   // partial attn accumulators (16 KB)
    __shared__ float4 s_attn[DV];      // final attn vector (2 KB)
    __shared__ float  s_redA[16];
    __shared__ float  s_redB[16];

    // ---- lane-private q segment: d in [lane*8, lane*8+8) ----
    const float4* q4 = reinterpret_cast<const float4*>(q + (size_t)b * D);
    const float4  qa = q4[lane * 2];
    const float4  qb = q4[lane * 2 + 1];

    const float4* kc4 = reinterpret_cast<const float4*>(kc + (size_t)b * L * D);
    const float4* kd4 = reinterpret_cast<const float4*>(kd + (size_t)b * L * D);

    // ---- Phase 1: col logits (q.kc) and diffuse gates (q.kd) ----
    // wave handles rows [wave*64, wave*64+64)
    for (int r = 0; r < 64; ++r) {
        const int l = wave * 64 + r;
        const float4* rowc = kc4 + (size_t)l * DV + lane * 2;
        const float4* rowd = kd4 + (size_t)l * DV + lane * 2;
        const float4 c0 = rowc[0], c1 = rowc[1];
        const float4 e0 = rowd[0], e1 = rowd[1];

        float dc = qa.x * c0.x + qa.y * c0.y + qa.z * c0.z + qa.w * c0.w
                 + qb.x * c1.x + qb.y * c1.y + qb.z * c1.z + qb.w * c1.w;
        float dd = qa.x * e0.x + qa.y * e0.y + qa.z * e0.z + qa.w * e0.w
                 + qb.x * e1.x + qb.y * e1.y + qb.z * e1.z + qb.w * e1.w;

        #pragma unroll
        for (int off = 32; off; off >>= 1) {
            dc += __shfl_xor(dc, off);
            dd += __shfl_xor(dd, off);
        }
        if (lane == 0) {
            s_col[l] = dc * INV_T;
            s_sig[l] = 1.0f / (1.0f + __expf(-dd * INV_T));
        }
    }
    __syncthreads();

    // ---- logits output (second tuple element) ----
    logits[(size_t)b * L + tid] = s_col[tid];

    // ---- Phase 2: softmax over L ----
    const float x = s_col[tid];
    float m = x;
    #pragma unroll
    for (int off = 32; off; off >>= 1) m = fmaxf(m, __shfl_xor(m, off));
    if (lane == 0) s_redA[wave] = m;
    __syncthreads();

    float gm = s_redA[0];
    #pragma unroll
    for (int i = 1; i < 16; ++i) gm = fmaxf(gm, s_redA[i]);

    const float e = __expf(x - gm);
    float ssum = e;
    #pragma unroll
    for (int off = 32; off; off >>= 1) ssum += __shfl_xor(ssum, off);
    if (lane == 0) s_redB[wave] = ssum;
    __syncthreads();

    float gs = 0.0f;
    #pragma unroll
    for (int i = 0; i < 16; ++i) gs += s_redB[i];

    s_col[tid] = e / gs;   // own element only: no race
    __syncthreads();

    // ---- Phase 3: attn[d] = sum_l w[l] * v[l,d] ----
    const float4* v4 = reinterpret_cast<const float4*>(v + (size_t)b * L * D);
    const int c = tid & 127;   // float4 column
    const int g = tid >> 7;    // l-group 0..7
    float4 acc = make_float4(0.f, 0.f, 0.f, 0.f);
    #pragma unroll 4
    for (int r = 0; r < 128; ++r) {
        const int l = g * 128 + r;
        const float w = s_col[l];
        const float4 vv = v4[(size_t)l * DV + c];
        acc.x += w * vv.x;
        acc.y += w * vv.y;
        acc.z += w * vv.z;
        acc.w += w * vv.w;
    }
    s_part[g][c] = acc;
    __syncthreads();

    if (tid < DV) {
        float4 a = s_part[0][tid];
        #pragma unroll
        for (int gg = 1; gg < 8; ++gg) {
            const float4 p = s_part[gg][tid];
            a.x += p.x; a.y += p.y; a.z += p.z; a.w += p.w;
        }
        s_attn[tid] = a;
    }
    __syncthreads();

    // ---- Phase 4: out[l,d] = sig[l] * attn[d] ----
    float4* out4 = reinterpret_cast<float4*>(out + (size_t)b * L * D);
    #pragma unroll 4
    for (int i = tid; i < L * DV; i += 1024) {
        const int l  = i >> 7;
        const int cc = i & 127;
        const float sg = s_sig[l];
        const float4 a = s_attn[cc];
        out4[i] = make_float4(sg * a.x, sg * a.y, sg * a.z, sg * a.w);
    }
}

extern "C" void kernel_launch(void* const* d_in, const int* in_sizes, int n_in,
                              void* d_out, int out_size, void* d_ws, size_t ws_size,
                              hipStream_t stream) {
    const float* q  = (const float*)d_in[0];
    const float* kc = (const float*)d_in[1];
    const float* kd = (const float*)d_in[2];
    const float* v  = (const float*)d_in[3];
    float* out    = (float*)d_out;                       // (B,L,D) flat
    float* logits = out + (size_t)B * L * D;             // (B,L) flat

    hipLaunchKernelGGL(cda_fused_kernel, dim3(B), dim3(1024), 0, stream,
                       q, kc, kd, v, out, logits);
}